// Round 3
// baseline (88.720 us; speedup 1.0000x reference)
//
#include <hip/hip_runtime.h>
#include <stdint.h>

// y[n,i] = relu(b[idx[n],i] + sum_o w[idx[n],i,o] * x[n,o])
// B=8192, 64 models, 256x256 fp32. Single fused kernel, 256 blocks
// (64 models x 2 sample-tiles x 2 out-tiles), 1 block/CU.
//  phase 1: per-block compaction of this model's sample ids (no atomics)
//  phase 2: stage FULL-K x-tile and w-tile into LDS as bf16 (132 KB of the
//           160 KB gfx950 workgroup LDS) in one deeply-pipelined load burst
//  phase 3: 128 MFMAs with NO barriers (3 __syncthreads total per kernel)

#define N_MODELS 64
#define IN_F     256
#define OUT_F    256
#define BATCH    8192
#define BM       128
#define BN       128
#define PK       264   // LDS row pitch in bf16: 256 + 8 (132 dwords = 4 mod 32
                       // -> MFMA-phase ds_read_b128 is 2-way = conflict-free)

typedef __bf16 bf16x8 __attribute__((ext_vector_type(8)));
typedef float  f32x4  __attribute__((ext_vector_type(4)));

__device__ __forceinline__ bf16x8 pack8(float4 a, float4 b) {
  bf16x8 o;                       // native casts -> v_cvt_pk_bf16_f32
  o[0] = (__bf16)a.x; o[1] = (__bf16)a.y; o[2] = (__bf16)a.z; o[3] = (__bf16)a.w;
  o[4] = (__bf16)b.x; o[5] = (__bf16)b.y; o[6] = (__bf16)b.z; o[7] = (__bf16)b.w;
  return o;
}

__global__ __launch_bounds__(256) void fused_kernel(
    const float* __restrict__ x, const int* __restrict__ idxs,
    const float* __restrict__ w, const float* __restrict__ bias_g,
    float* __restrict__ out) {
  const int model = blockIdx.x >> 2;
  const int tile  = (blockIdx.x >> 1) & 1;
  const int i0    = (blockIdx.x & 1) * BN;
  const int t     = threadIdx.x;
  const int lane  = t & 63;
  const int wv    = t >> 6;

  __shared__ unsigned short a_lds[BM][PK];  // gathered x, bf16, [m][k]
  __shared__ unsigned short b_lds[BN][PK];  // w rows,    bf16, [i][k]
  __shared__ int rid[BM];
  __shared__ int wsum[4];

  const int rw = t >> 1;   // staged row, 2 threads/row
  const int h  = t & 1;    // which 128-float half of the 256-float row

  // ---- idx loads first so compaction data is in flight under w staging ----
  const int4* ip = (const int4*)idxs + t * 8;
  int4 iv[8];
#pragma unroll
  for (int j = 0; j < 8; ++j) iv[j] = ip[j];

  // ---- w staging (tile0 blocks: before compaction; they never early-exit) ----
  const float* wrow = w + (size_t)model * (IN_F * OUT_F)
                        + (size_t)(i0 + rw) * IN_F + h * 128;
  if (tile == 0) {
#pragma unroll
    for (int j = 0; j < 16; ++j) {
      float4 a = *(const float4*)(wrow + j * 8);
      float4 b = *(const float4*)(wrow + j * 8 + 4);
      *(bf16x8*)&b_lds[rw][h * 128 + j * 8] = pack8(a, b);
    }
  }

  if (t < BM) rid[t] = -1;

  // ---- phase 1: compaction (thread t owns idxs[t*32 .. t*32+31]) ----
  int cnt = 0;
#pragma unroll
  for (int j = 0; j < 8; ++j) {
    int4 v = iv[j];
    cnt += (v.x == model) + (v.y == model) + (v.z == model) + (v.w == model);
  }
  int inc = cnt;
#pragma unroll
  for (int d = 1; d < 64; d <<= 1) {
    int u = __shfl_up(inc, d);
    if (lane >= d) inc += u;
  }
  if (lane == 63) wsum[wv] = inc;
  __syncthreads();                       // rid init + wsum ready
  int wpre = 0, total = 0;
#pragma unroll
  for (int j = 0; j < 4; ++j) {
    int s = wsum[j];
    total += s;
    if (j < wv) wpre += s;
  }
  const int start = tile * BM;
  if (start >= total) return;            // block-uniform (empty tile-1 blocks
                                         // exit BEFORE reading any w)
  int off = wpre + inc - cnt - start;
#pragma unroll
  for (int j = 0; j < 8; ++j) {
    int4 v = iv[j];
    int n0 = t * 32 + j * 4;
    if (v.x == model) { if ((unsigned)off < BM) rid[off] = n0 + 0; ++off; }
    if (v.y == model) { if ((unsigned)off < BM) rid[off] = n0 + 1; ++off; }
    if (v.z == model) { if ((unsigned)off < BM) rid[off] = n0 + 2; ++off; }
    if (v.w == model) { if ((unsigned)off < BM) rid[off] = n0 + 3; ++off; }
  }
  __syncthreads();                       // rid ready

  // ---- w staging for tile1 blocks (only after proving non-empty) ----
  if (tile == 1) {
#pragma unroll
    for (int j = 0; j < 16; ++j) {
      float4 a = *(const float4*)(wrow + j * 8);
      float4 b = *(const float4*)(wrow + j * 8 + 4);
      *(bf16x8*)&b_lds[rw][h * 128 + j * 8] = pack8(a, b);
    }
  }

  // ---- x staging (gathered rows; invalid rows read row 0, never stored) ----
  const int srow = rid[rw];
  const float* xrow = x + (size_t)(srow < 0 ? 0 : srow) * IN_F + h * 128;
#pragma unroll
  for (int j = 0; j < 16; ++j) {
    float4 a = *(const float4*)(xrow + j * 8);
    float4 b = *(const float4*)(xrow + j * 8 + 4);
    *(bf16x8*)&a_lds[rw][h * 128 + j * 8] = pack8(a, b);
  }

  // bias (issued while staging loads drain)
  const int wm   = (wv & 1) * 64;
  const int wn   = (wv >> 1) * 64;
  const int col  = lane & 15;
  const int quad = lane >> 4;
  float bv[4];
  const float* bp = bias_g + model * OUT_F + i0 + wn + col;
#pragma unroll
  for (int nt = 0; nt < 4; ++nt) bv[nt] = bp[nt * 16];

  __syncthreads();                       // tiles ready; last barrier

  f32x4 acc[4][4];                       // bias folded into accumulator init
#pragma unroll
  for (int mt = 0; mt < 4; ++mt)
#pragma unroll
    for (int nt = 0; nt < 4; ++nt)
      acc[mt][nt] = (f32x4){bv[nt], bv[nt], bv[nt], bv[nt]};

  // ---- phase 3: 8 k-steps x 16 MFMA, zero barriers ----
#pragma unroll
  for (int ks = 0; ks < 8; ++ks) {
    bf16x8 af[4], bfr[4];
#pragma unroll
    for (int mt = 0; mt < 4; ++mt)
      af[mt] = *(const bf16x8*)&a_lds[wm + mt * 16 + col][ks * 32 + quad * 8];
#pragma unroll
    for (int nt = 0; nt < 4; ++nt)
      bfr[nt] = *(const bf16x8*)&b_lds[wn + nt * 16 + col][ks * 32 + quad * 8];
#pragma unroll
    for (int mt = 0; mt < 4; ++mt)
#pragma unroll
      for (int nt = 0; nt < 4; ++nt)
        acc[mt][nt] = __builtin_amdgcn_mfma_f32_16x16x32_bf16(
            af[mt], bfr[nt], acc[mt][nt], 0, 0, 0);
  }

  // ---- epilogue: relu + scatter by sample id ----
#pragma unroll
  for (int mt = 0; mt < 4; ++mt) {
#pragma unroll
    for (int reg = 0; reg < 4; ++reg) {
      const int mm = wm + mt * 16 + quad * 4 + reg;   // C/D: row = quad*4+reg
      const int s = rid[mm];
      if (s >= 0) {
        float* orow = out + (size_t)s * OUT_F + i0 + wn + col;
#pragma unroll
        for (int nt = 0; nt < 4; ++nt)
          orow[nt * 16] = fmaxf(acc[mt][nt][reg], 0.0f);
      }
    }
  }
}

extern "C" void kernel_launch(void* const* d_in, const int* in_sizes, int n_in,
                              void* d_out, int out_size, void* d_ws, size_t ws_size,
                              hipStream_t stream) {
  const float* x    = (const float*)d_in[0];
  const int*   idxs = (const int*)d_in[1];
  const float* w    = (const float*)d_in[2];
  const float* b    = (const float*)d_in[3];
  float* out = (float*)d_out;
  (void)d_ws; (void)ws_size;

  fused_kernel<<<N_MODELS * 4, 256, 0, stream>>>(x, idxs, w, b, out);
}

// Round 4
// 85.769 us; speedup vs baseline: 1.0344x; 1.0344x over previous
//
#include <hip/hip_runtime.h>
#include <stdint.h>

// y[n,i] = relu(b[idx[n],i] + sum_o w[idx[n],i,o] * x[n,o])
// B=8192, 64 models, 256x256 fp32. Single fused kernel, 256 blocks
// (64 models x 2 sample-tiles x 2 out-tiles), 1024 threads (16 waves =
// 4/SIMD for staging-latency hiding), full-K LDS tiles, no K-loop barriers.

#define N_MODELS 64
#define IN_F     256
#define OUT_F    256
#define BATCH    8192
#define BM       128
#define BN       128
#define PK       264   // LDS pitch bf16: 256+8 -> rows shift 4 banks; b128
                       // fragment reads are 2-way = conflict-free (m136)

typedef __bf16 bf16x8 __attribute__((ext_vector_type(8)));
typedef float  f32x4  __attribute__((ext_vector_type(4)));

__device__ __forceinline__ bf16x8 pack8(float4 a, float4 b) {
  bf16x8 o;                       // native casts -> v_cvt_pk_bf16_f32
  o[0] = (__bf16)a.x; o[1] = (__bf16)a.y; o[2] = (__bf16)a.z; o[3] = (__bf16)a.w;
  o[4] = (__bf16)b.x; o[5] = (__bf16)b.y; o[6] = (__bf16)b.z; o[7] = (__bf16)b.w;
  return o;
}

__global__ __launch_bounds__(1024) void fused_kernel(
    const float* __restrict__ x, const int* __restrict__ idxs,
    const float* __restrict__ w, const float* __restrict__ bias_g,
    float* __restrict__ out) {
  const int model = blockIdx.x >> 2;
  const int tile  = (blockIdx.x >> 1) & 1;
  const int i0    = (blockIdx.x & 1) * BN;
  const int t     = threadIdx.x;
  const int lane  = t & 63;
  const int wv    = t >> 6;          // 0..15

  __shared__ unsigned short a_lds[BM][PK];  // gathered x rows, bf16
  __shared__ unsigned short b_lds[BN][PK];  // w rows, bf16
  __shared__ int rid[BM];
  __shared__ int wsum[16];

  const int rw = t >> 3;   // staged row (8 threads/row)
  const int h  = t & 7;    // 32-float chunk within the row

  // ---- idx loads first (compaction input in flight under w staging) ----
  const int4* ip = (const int4*)idxs + t * 2;   // 8 idxs/thread
  int4 iv0 = ip[0], iv1 = ip[1];

  const float* wrow = w + (size_t)model * (IN_F * OUT_F)
                        + (size_t)(i0 + rw) * IN_F + h * 32;

  // ---- w staging, tile0 blocks (they never early-exit) ----
  if (tile == 0) {
    float4 tw[8];
#pragma unroll
    for (int j = 0; j < 8; ++j) tw[j] = *(const float4*)(wrow + j * 4);  // 8 deep
#pragma unroll
    for (int j = 0; j < 4; ++j)
      *(bf16x8*)&b_lds[rw][h * 32 + j * 8] = pack8(tw[2 * j], tw[2 * j + 1]);
  }

  if (t < BM) rid[t] = -1;

  // ---- phase 1: compaction (thread t owns idxs[8t .. 8t+7]) ----
  int cnt = (iv0.x == model) + (iv0.y == model) + (iv0.z == model) + (iv0.w == model)
          + (iv1.x == model) + (iv1.y == model) + (iv1.z == model) + (iv1.w == model);
  int inc = cnt;
#pragma unroll
  for (int d = 1; d < 64; d <<= 1) {
    int u = __shfl_up(inc, d);
    if (lane >= d) inc += u;
  }
  if (lane == 63) wsum[wv] = inc;
  __syncthreads();
  int wpre = 0, total = 0;
#pragma unroll
  for (int j = 0; j < 16; ++j) {
    int s = wsum[j];
    total += s;
    if (j < wv) wpre += s;
  }
  const int start = tile * BM;
  if (start >= total) return;          // block-uniform; empty tile1 exits
                                       // before touching w
  int off = wpre + inc - cnt - start;
  {
    int n0 = t * 8;
    if (iv0.x == model) { if ((unsigned)off < BM) rid[off] = n0 + 0; ++off; }
    if (iv0.y == model) { if ((unsigned)off < BM) rid[off] = n0 + 1; ++off; }
    if (iv0.z == model) { if ((unsigned)off < BM) rid[off] = n0 + 2; ++off; }
    if (iv0.w == model) { if ((unsigned)off < BM) rid[off] = n0 + 3; ++off; }
    if (iv1.x == model) { if ((unsigned)off < BM) rid[off] = n0 + 4; ++off; }
    if (iv1.y == model) { if ((unsigned)off < BM) rid[off] = n0 + 5; ++off; }
    if (iv1.z == model) { if ((unsigned)off < BM) rid[off] = n0 + 6; ++off; }
    if (iv1.w == model) { if ((unsigned)off < BM) rid[off] = n0 + 7; ++off; }
  }
  __syncthreads();                     // rid ready

  // ---- w staging for tile1 (after proving non-empty) ----
  if (tile == 1) {
    float4 tw[8];
#pragma unroll
    for (int j = 0; j < 8; ++j) tw[j] = *(const float4*)(wrow + j * 4);
#pragma unroll
    for (int j = 0; j < 4; ++j)
      *(bf16x8*)&b_lds[rw][h * 32 + j * 8] = pack8(tw[2 * j], tw[2 * j + 1]);
  }

  // ---- x staging (gathered rows; invalid rows read row 0, never stored) ----
  const int srow = rid[rw];
  const float* xrow = x + (size_t)(srow < 0 ? 0 : srow) * IN_F + h * 32;
  {
    float4 tx[8];
#pragma unroll
    for (int j = 0; j < 8; ++j) tx[j] = *(const float4*)(xrow + j * 4);
#pragma unroll
    for (int j = 0; j < 4; ++j)
      *(bf16x8*)&a_lds[rw][h * 32 + j * 8] = pack8(tx[2 * j], tx[2 * j + 1]);
  }

  // bias (issued while staging drains)
  const int wm   = (wv & 3) * 32;      // 4x4 wave grid of 32x32 tiles
  const int wn   = (wv >> 2) * 32;
  const int col  = lane & 15;
  const int quad = lane >> 4;
  float bv[2];
  const float* bp = bias_g + model * OUT_F + i0 + wn + col;
#pragma unroll
  for (int nt = 0; nt < 2; ++nt) bv[nt] = bp[nt * 16];

  __syncthreads();                     // tiles ready; last barrier

  f32x4 acc[2][2];                     // bias folded into acc init
#pragma unroll
  for (int mt = 0; mt < 2; ++mt)
#pragma unroll
    for (int nt = 0; nt < 2; ++nt)
      acc[mt][nt] = (f32x4){bv[nt], bv[nt], bv[nt], bv[nt]};

  // ---- phase 3: 8 k-steps x 4 MFMA per wave, zero barriers ----
#pragma unroll
  for (int ks = 0; ks < 8; ++ks) {
    bf16x8 af[2], bfr[2];
#pragma unroll
    for (int mt = 0; mt < 2; ++mt)
      af[mt] = *(const bf16x8*)&a_lds[wm + mt * 16 + col][ks * 32 + quad * 8];
#pragma unroll
    for (int nt = 0; nt < 2; ++nt)
      bfr[nt] = *(const bf16x8*)&b_lds[wn + nt * 16 + col][ks * 32 + quad * 8];
#pragma unroll
    for (int mt = 0; mt < 2; ++mt)
#pragma unroll
      for (int nt = 0; nt < 2; ++nt)
        acc[mt][nt] = __builtin_amdgcn_mfma_f32_16x16x32_bf16(
            af[mt], bfr[nt], acc[mt][nt], 0, 0, 0);
  }

  // ---- epilogue: relu + scatter by sample id ----
#pragma unroll
  for (int mt = 0; mt < 2; ++mt) {
#pragma unroll
    for (int reg = 0; reg < 4; ++reg) {
      const int mm = wm + mt * 16 + quad * 4 + reg;   // C/D: row = quad*4+reg
      const int s = rid[mm];
      if (s >= 0) {
        float* orow = out + (size_t)s * OUT_F + i0 + wn + col;
#pragma unroll
        for (int nt = 0; nt < 2; ++nt)
          orow[nt * 16] = fmaxf(acc[mt][nt][reg], 0.0f);
      }
    }
  }
}

extern "C" void kernel_launch(void* const* d_in, const int* in_sizes, int n_in,
                              void* d_out, int out_size, void* d_ws, size_t ws_size,
                              hipStream_t stream) {
  const float* x    = (const float*)d_in[0];
  const int*   idxs = (const int*)d_in[1];
  const float* w    = (const float*)d_in[2];
  const float* b    = (const float*)d_in[3];
  float* out = (float*)d_out;
  (void)d_ws; (void)ws_size;

  fused_kernel<<<N_MODELS * 4, 1024, 0, stream>>>(x, idxs, w, b, out);
}